// Round 15
// baseline (124.297 us; speedup 1.0000x reference)
//
#include <hip/hip_runtime.h>
#include <math.h>

#define BB 2
#define SS 2048
#define DIMM 1024
#define HH 16
#define DD 64
#define WINDOW 512

typedef __bf16 bf16x8 __attribute__((ext_vector_type(8)));
typedef __bf16 bf16x4 __attribute__((ext_vector_type(4)));
typedef float f32x4 __attribute__((ext_vector_type(4)));

__device__ __forceinline__ unsigned short f2bf(float f) {
    unsigned int u = __float_as_uint(f);
    u = (u + 0x7FFFu + ((u >> 16) & 1u)) >> 16;
    return (unsigned short)u;
}
__device__ __forceinline__ float bf2f(unsigned short u) {
    return __uint_as_float((unsigned int)u << 16);
}

__device__ __forceinline__ void async_cp16(unsigned short* lds_dst, const unsigned short* g_src) {
    __builtin_amdgcn_global_load_lds(
        (const __attribute__((address_space(1))) unsigned int*)g_src,
        (__attribute__((address_space(3))) unsigned int*)lds_dst, 16, 0, 0);
}

// ------------------------------------------------------------------
// prep_all: fused weight transposes (blocks 0-4095), tokens->bf16
// (4096-6143), [Wg|Wmix] pack (6144-6271), epstart (6272-6287)
// ------------------------------------------------------------------
__global__ __launch_bounds__(256) void prep_all_kernel(
    const float* __restrict__ tokens, unsigned short* __restrict__ tokA,
    const float* __restrict__ Wq, const float* __restrict__ Wkv,
    const float* __restrict__ Wo, unsigned short* __restrict__ BtW,
    unsigned short* __restrict__ WotW,
    const float* __restrict__ Wg, const float* __restrict__ Wmix,
    unsigned short* __restrict__ wgmt,
    const int* __restrict__ ep, int* __restrict__ epstart)
{
    int bid = blockIdx.x;
    int tid = threadIdx.x;
    if (bid < 4096) {
        const float* src;
        unsigned short* dst;
        int C, bx, by;
        if (bid < 1024) {
            src = Wq; dst = BtW; C = 1024; bx = bid & 31; by = bid >> 5;
        } else if (bid < 3072) {
            int rel = bid - 1024;
            src = Wkv; dst = BtW + 1024 * 1024; C = 2048; bx = rel & 63; by = rel >> 6;
        } else {
            int rel = bid - 3072;
            src = Wo; dst = WotW; C = 1024; bx = rel & 31; by = rel >> 5;
        }
        const int R = 1024;
        __shared__ float t[32][33];
        int c0 = bx * 32, r0 = by * 32;
        int tx = tid & 31, ty = tid >> 5;
        #pragma unroll
        for (int u = 0; u < 4; ++u)
            t[ty + 8 * u][tx] = src[(size_t)(r0 + ty + 8 * u) * C + c0 + tx];
        __syncthreads();
        #pragma unroll
        for (int u = 0; u < 4; ++u)
            dst[(size_t)(c0 + ty + 8 * u) * R + r0 + tx] = f2bf(t[tx][ty + 8 * u]);
    } else if (bid < 6144) {
        const int n4 = (BB * SS * DIMM) / 4;
        for (int i = (bid - 4096) * 256 + tid; i < n4; i += 2048 * 256) {
            float4 v = ((const float4*)tokens)[i];
            ushort4 o;
            o.x = f2bf(v.x); o.y = f2bf(v.y); o.z = f2bf(v.z); o.w = f2bf(v.w);
            ((ushort4*)tokA)[i] = o;
        }
    } else if (bid < 6272) {
        int idx = (bid - 6144) * 256 + tid;
        int n = idx >> 10, k = idx & 1023;
        const float* src = (n < 16) ? Wg : Wmix;
        wgmt[idx] = f2bf(src[k * HH + (n & 15)]);
    } else {
        int idx = (bid - 6272) * 256 + tid;
        int b = idx >> 11, i = idx & 2047;
        const int* e = ep + b * SS;
        int v = e[i];
        int lo = 0, hi = i;
        while (lo < hi) {
            int mid = (lo + hi) >> 1;
            if (e[mid] == v) hi = mid; else lo = mid + 1;
        }
        epstart[idx] = lo;
    }
}

// ------------------------------------------------------------------
// projmix: blocks 0-767 = proj GEMM (128x128, 2-buffer, R6 structure,
// RoPE fused in epilogue for q/k, scatter -> bf16 q/k/v);
// blocks 768-1023 = mixgate MFMA.
// ------------------------------------------------------------------
__global__ __launch_bounds__(256) void projmix_kernel(
    const unsigned short* __restrict__ A, const unsigned short* __restrict__ Bt,
    unsigned short* __restrict__ qo, unsigned short* __restrict__ ko,
    unsigned short* __restrict__ vo,
    const unsigned short* __restrict__ wgmt,
    float* __restrict__ gate, float* __restrict__ mix)
{
    __shared__ unsigned short As[2][128 * 32];
    __shared__ unsigned short Bs[2][128 * 32];
    __shared__ float red[4][16][32];

    const int K = 1024;
    int bid = blockIdx.x;
    int tid = threadIdx.x;
    int lane = tid & 63;
    int wave = tid >> 6;
    int fr = lane & 15, hi = lane >> 4;

    if (bid < 768) {
        int nbase = (bid % 24) * 128;
        int mbase = (bid / 24) * 128;
        int wr = wave >> 1, wc = wave & 1;
        int region = nbase >> 10;                // 0=q, 1=k, 2=v (block-uniform)

        int srow = tid >> 2;
        int sp   = tid & 3;
        int scol = (sp ^ ((srow >> 1) & 3)) * 8;
        const unsigned short* agp0 = A  + (size_t)(mbase + srow) * K + scol;
        const unsigned short* agp1 = A  + (size_t)(mbase + srow + 64) * K + scol;
        const unsigned short* bgp0 = Bt + (size_t)(nbase + srow) * K + scol;
        const unsigned short* bgp1 = Bt + (size_t)(nbase + srow + 64) * K + scol;

        f32x4 acc[4][4];
        #pragma unroll
        for (int m_ = 0; m_ < 4; ++m_)
            #pragma unroll
            for (int n_ = 0; n_ < 4; ++n_)
                acc[m_][n_] = (f32x4){0.f, 0.f, 0.f, 0.f};

        int aidx[4], bidx[4];
        #pragma unroll
        for (int m_ = 0; m_ < 4; ++m_) {
            int row = wr * 64 + m_ * 16 + fr;
            aidx[m_] = row * 32 + (hi ^ ((row >> 1) & 3)) * 8;
        }
        #pragma unroll
        for (int n_ = 0; n_ < 4; ++n_) {
            int row = wc * 64 + n_ * 16 + fr;
            bidx[n_] = row * 32 + (hi ^ ((row >> 1) & 3)) * 8;
        }

        auto stage = [&](int buf, int k0) {
            async_cp16(&As[buf][tid * 8], agp0 + k0);
            async_cp16(&As[buf][2048 + tid * 8], agp1 + k0);
            async_cp16(&Bs[buf][tid * 8], bgp0 + k0);
            async_cp16(&Bs[buf][2048 + tid * 8], bgp1 + k0);
        };

        stage(0, 0);
        for (int k0 = 0; k0 < K; k0 += 32) {
            int cur = (k0 >> 5) & 1;
            __syncthreads();
            if (k0 + 32 < K) stage(cur ^ 1, k0 + 32);

            bf16x8 af[4], bfr[4];
            #pragma unroll
            for (int m_ = 0; m_ < 4; ++m_) af[m_] = *(const bf16x8*)&As[cur][aidx[m_]];
            #pragma unroll
            for (int n_ = 0; n_ < 4; ++n_) bfr[n_] = *(const bf16x8*)&Bs[cur][bidx[n_]];
            #pragma unroll
            for (int m_ = 0; m_ < 4; ++m_)
                #pragma unroll
                for (int n_ = 0; n_ < 4; ++n_)
                    acc[m_][n_] = __builtin_amdgcn_mfma_f32_16x16x32_bf16(
                        af[m_], bfr[n_], acc[m_][n_], 0, 0, 0);
        }

        // fused RoPE for q/k: pair (d, d^1) lives in lane^1 (same hi)
        if (region < 2) {
            float scl = (region == 0) ? 0.125f : 1.f;
            #pragma unroll
            for (int n_ = 0; n_ < 4; ++n_) {
                int d = n_ * 16 + fr;
                float invf = powf(10000.f, -(float)(d & ~1) * (1.f / 64.f));
                #pragma unroll
                for (int m_ = 0; m_ < 4; ++m_) {
                    #pragma unroll
                    for (int j = 0; j < 4; ++j) {
                        int mg = mbase + wr * 64 + m_ * 16 + hi * 4 + j;
                        int s = mg & 2047;
                        float x = acc[m_][n_][j];
                        float p = __shfl_xor(x, 1, 64);
                        float ang = (float)s * invf;
                        float rr = ang - 6.2831853f * floorf(ang * 0.15915494f);
                        float cs, sn;
                        __sincosf(rr, &sn, &cs);
                        float val = (fr & 1) ? (x * cs + p * sn) : (x * cs - p * sn);
                        acc[m_][n_][j] = val * scl;
                    }
                }
            }
        }

        #pragma unroll
        for (int m_ = 0; m_ < 4; ++m_) {
            #pragma unroll
            for (int n_ = 0; n_ < 4; ++n_) {
                int c = nbase + wc * 64 + n_ * 16 + fr;
                int cc = c & 1023, h = cc >> 6, d = cc & 63;
                unsigned short* dst = (c < 1024) ? qo : (c < 2048) ? ko : vo;
                #pragma unroll
                for (int j = 0; j < 4; ++j) {
                    int mg = mbase + wr * 64 + m_ * 16 + hi * 4 + j;
                    int b = mg >> 11, s = mg & 2047;
                    dst[(((size_t)b * HH + h) * SS + s) * DD + d] = f2bf(acc[m_][n_][j]);
                }
            }
        }
    } else {
        // mixgate: sigmoid(tokens_bf16 @ Wgm^T), 16 rows per block
        int mbase = (bid - 768) * 16;
        int kw = wave * 256;

        f32x4 acc[2];
        acc[0] = (f32x4){0.f, 0.f, 0.f, 0.f};
        acc[1] = (f32x4){0.f, 0.f, 0.f, 0.f};

        const unsigned short* a0 = A + (size_t)(mbase + fr) * 1024 + kw + hi * 8;
        const unsigned short* b0 = wgmt + (size_t)fr * 1024 + kw + hi * 8;
        const unsigned short* b1 = wgmt + (size_t)(16 + fr) * 1024 + kw + hi * 8;

        #pragma unroll 2
        for (int k = 0; k < 256; k += 32) {
            bf16x8 af0 = *(const bf16x8*)(a0 + k);
            bf16x8 bf0 = *(const bf16x8*)(b0 + k);
            bf16x8 bf1 = *(const bf16x8*)(b1 + k);
            acc[0] = __builtin_amdgcn_mfma_f32_16x16x32_bf16(af0, bf0, acc[0], 0, 0, 0);
            acc[1] = __builtin_amdgcn_mfma_f32_16x16x32_bf16(af0, bf1, acc[1], 0, 0, 0);
        }

        #pragma unroll
        for (int n_ = 0; n_ < 2; ++n_)
            #pragma unroll
            for (int j = 0; j < 4; ++j)
                red[wave][hi * 4 + j][n_ * 16 + fr] = acc[n_][j];
        __syncthreads();

        #pragma unroll
        for (int e = 0; e < 2; ++e) {
            int idx = tid * 2 + e;
            int r = idx >> 5, c = idx & 31;
            float s4 = red[0][r][c] + red[1][r][c] + red[2][r][c] + red[3][r][c];
            float sg = 1.f / (1.f + __expf(-s4));
            int mg = mbase + r;
            int b = mg >> 11, s = mg & 2047;
            int h = c & 15;
            float* dst = (c < 16) ? gate : mix;
            dst[((size_t)b * HH + h) * SS + s] = sg;
        }
    }
}

// ------------------------------------------------------------------
// bf16 MFMA GEMM (output GEMM), 2-buffer prefetch, R6 structure
// ------------------------------------------------------------------
template<int BM, int BN>
__global__ __launch_bounds__(256) void gemm_mfma(
    const unsigned short* __restrict__ A, const unsigned short* __restrict__ Bt,
    float* __restrict__ C)
{
    const int K = 1024;
    constexpr int MFR = BM / 32;
    constexpr int NFR = BN / 32;
    int nbase = blockIdx.x * BN;
    int mbase = blockIdx.y * BM;

    int tid = threadIdx.x;
    int lane = tid & 63;
    int wave = tid >> 6;
    int wr = wave >> 1, wc = wave & 1;
    int fr = lane & 15, hi = lane >> 4;

    __shared__ unsigned short As[2][BM * 32];
    __shared__ unsigned short Bs[2][BN * 32];

    int srow = tid >> 2;
    int sp   = tid & 3;
    int scol = (sp ^ ((srow >> 1) & 3)) * 8;
    const unsigned short* agp0 = A  + (size_t)(mbase + srow) * K + scol;
    const unsigned short* agp1 = (BM == 128)
        ? A + (size_t)(mbase + srow + 64) * K + scol : agp0;
    const unsigned short* bgp0 = Bt + (size_t)(nbase + srow) * K + scol;
    const unsigned short* bgp1 = (BN == 128)
        ? Bt + (size_t)(nbase + srow + 64) * K + scol : bgp0;

    f32x4 acc[MFR][NFR];
    #pragma unroll
    for (int m_ = 0; m_ < MFR; ++m_)
        #pragma unroll
        for (int n_ = 0; n_ < NFR; ++n_)
            acc[m_][n_] = (f32x4){0.f, 0.f, 0.f, 0.f};

    int aidx[MFR], bidx[NFR];
    #pragma unroll
    for (int m_ = 0; m_ < MFR; ++m_) {
        int row = wr * (BM / 2) + m_ * 16 + fr;
        aidx[m_] = row * 32 + (hi ^ ((row >> 1) & 3)) * 8;
    }
    #pragma unroll
    for (int n_ = 0; n_ < NFR; ++n_) {
        int row = wc * (BN / 2) + n_ * 16 + fr;
        bidx[n_] = row * 32 + (hi ^ ((row >> 1) & 3)) * 8;
    }

    auto stage = [&](int buf, int k0) {
        async_cp16(&As[buf][tid * 8], agp0 + k0);
        if constexpr (BM == 128)
            async_cp16(&As[buf][2048 + tid * 8], agp1 + k0);
        async_cp16(&Bs[buf][tid * 8], bgp0 + k0);
        if constexpr (BN == 128)
            async_cp16(&Bs[buf][2048 + tid * 8], bgp1 + k0);
    };

    stage(0, 0);
    for (int k0 = 0; k0 < K; k0 += 32) {
        int cur = (k0 >> 5) & 1;
        __syncthreads();
        if (k0 + 32 < K) stage(cur ^ 1, k0 + 32);

        bf16x8 af[MFR], bfr[NFR];
        #pragma unroll
        for (int m_ = 0; m_ < MFR; ++m_) af[m_] = *(const bf16x8*)&As[cur][aidx[m_]];
        #pragma unroll
        for (int n_ = 0; n_ < NFR; ++n_) bfr[n_] = *(const bf16x8*)&Bs[cur][bidx[n_]];
        #pragma unroll
        for (int m_ = 0; m_ < MFR; ++m_)
            #pragma unroll
            for (int n_ = 0; n_ < NFR; ++n_)
                acc[m_][n_] = __builtin_amdgcn_mfma_f32_16x16x32_bf16(
                    af[m_], bfr[n_], acc[m_][n_], 0, 0, 0);
    }

    #pragma unroll
    for (int m_ = 0; m_ < MFR; ++m_) {
        #pragma unroll
        for (int n_ = 0; n_ < NFR; ++n_) {
            int c = nbase + wc * (BN / 2) + n_ * 16 + fr;
            #pragma unroll
            for (int j = 0; j < 4; ++j) {
                int mg = mbase + wr * (BM / 2) + m_ * 16 + hi * 4 + j;
                C[(size_t)mg * 1024 + c] = acc[m_][n_][j];
            }
        }
    }
}

// ------------------------------------------------------------------
// V lerp with value_residual -> V^T bf16 [bh][d][s]
// ------------------------------------------------------------------
__global__ __launch_bounds__(256) void vlerp_t_kernel(
    const unsigned short* __restrict__ v0, const float* __restrict__ vres,
    const float* __restrict__ mix, unsigned short* __restrict__ vt)
{
    int st = blockIdx.x;
    int bh = blockIdx.y;
    int tid = threadIdx.x;
    int sl = tid >> 2;
    int dg = (tid & 3) * 16;
    int s = st * 64 + sl;
    size_t rowoff = ((size_t)bh * SS + s) * DD + dg;

    __shared__ unsigned short vtile[64][66];

    union { uint4 v[2]; unsigned short u[16]; } va;
    va.v[0] = *(const uint4*)(v0 + rowoff);
    va.v[1] = *(const uint4*)(v0 + rowoff + 8);
    float4 w[4];
    #pragma unroll
    for (int u = 0; u < 4; ++u) w[u] = *(const float4*)(vres + rowoff + 4 * u);
    float mx = mix[(size_t)bh * SS + s];

    #pragma unroll
    for (int e = 0; e < 16; ++e) {
        float vv = bf2f(va.u[e]);
        float wr = ((const float*)w)[e];
        vtile[sl][dg + e] = f2bf(vv + mx * (wr - vv));
    }
    __syncthreads();

    int d = tid >> 2;
    int sseg = (tid & 3) * 16;
    union { uint4 v[2]; unsigned short u[16]; } ot;
    #pragma unroll
    for (int e = 0; e < 16; ++e) ot.u[e] = vtile[sseg + e][d];
    unsigned short* dst = vt + ((size_t)bh * DD + d) * SS + st * 64 + sseg;
    *(uint4*)dst = ot.v[0];
    *(uint4*)(dst + 8) = ot.v[1];
}

// ------------------------------------------------------------------
// MFMA flash attention: 8 waves x 16 queries (128-q tile), KVBLK=64,
// single-buffer LDS staging, XCD-swizzled grid of 512
// ------------------------------------------------------------------
__global__ __launch_bounds__(512) void attn_mfma(
    const unsigned short* __restrict__ qbh, const unsigned short* __restrict__ kbh,
    const unsigned short* __restrict__ vt, const int* __restrict__ epstart,
    const float* __restrict__ gate, unsigned short* __restrict__ ao)
{
    int orig = blockIdx.x;
    int swz  = (orig & 7) * 64 + (orig >> 3);
    int bh = swz >> 4, qt = swz & 15;
    int b = bh >> 4, h = bh & 15;
    int q0 = qt * 128;
    int tid = threadIdx.x;
    int wave = tid >> 6, lane = tid & 63;
    int lq = lane & 15, lg = lane >> 4;
    int i = q0 + wave * 16 + lq;

    __shared__ unsigned short Ks[4096];
    __shared__ unsigned short Vs[4096];
    alignas(16) __shared__ unsigned short P_lds[8][16][72];

    int srow = tid >> 3;
    int sc = (((tid & 7) ^ (srow & 7)) << 3);
    const unsigned short* kS = kbh + ((size_t)bh * SS + srow) * DD + sc;
    const unsigned short* vS = vt + ((size_t)bh * DD + srow) * SS + sc;

    int fidx[4];
    #pragma unroll
    for (int n = 0; n < 4; ++n) {
        int r = 16 * n + lq;
        fidx[n] = r * 64 + ((lg ^ (r & 7)) << 3);
    }

    const unsigned short* qrow = qbh + ((size_t)bh * SS + i) * DD + lg * 8;
    bf16x8 bq0 = *(const bf16x8*)qrow;
    bf16x8 bq1 = *(const bf16x8*)(qrow + 32);

    int jmin = i - WINDOW;
    int es = epstart[b * SS + i];
    if (es > jmin) jmin = es;
    float gi = gate[(size_t)bh * SS + i];

    float m = -1e30f, l = 0.f;
    f32x4 o[4];
    #pragma unroll
    for (int n = 0; n < 4; ++n) o[n] = (f32x4){0.f, 0.f, 0.f, 0.f};

    int jt0 = (q0 >= 512) ? ((q0 - 512) >> 6) : 0;
    int jt1 = (q0 + 127) >> 6;
    int nt = jt1 - jt0 + 1;
    int jb0 = jt0 * 64;

    for (int u = 0; u < nt; ++u) {
        int jbase = jb0 + 64 * u;

        __syncthreads();
        async_cp16(&Ks[tid * 8], kS + (size_t)jbase * DD);
        async_cp16(&Vs[tid * 8], vS + jbase);
        __syncthreads();

        f32x4 acc[4];
        #pragma unroll
        for (int n = 0; n < 4; ++n) acc[n] = (f32x4){0.f, 0.f, 0.f, 0.f};
        __builtin_amdgcn_s_setprio(1);
        #pragma unroll
        for (int n = 0; n < 4; ++n) {
            bf16x8 kf0 = *(const bf16x8*)&Ks[fidx[n]];
            bf16x8 kf1 = *(const bf16x8*)&Ks[fidx[n] ^ 32];
            acc[n] = __builtin_amdgcn_mfma_f32_16x16x32_bf16(kf0, bq0, acc[n], 0, 0, 0);
            acc[n] = __builtin_amdgcn_mfma_f32_16x16x32_bf16(kf1, bq1, acc[n], 0, 0, 0);
        }
        __builtin_amdgcn_s_setprio(0);

        int jb = jbase + lg * 4;
        #pragma unroll
        for (int n = 0; n < 4; ++n)
            #pragma unroll
            for (int r = 0; r < 4; ++r) {
                int j = jb + 16 * n + r;
                if (j < jmin || j > i) acc[n][r] = -3e38f;
            }

        float tm = -3e38f;
        #pragma unroll
        for (int n = 0; n < 4; ++n)
            tm = fmaxf(tm, fmaxf(fmaxf(acc[n][0], acc[n][1]), fmaxf(acc[n][2], acc[n][3])));
        tm = fmaxf(tm, __shfl_xor(tm, 16, 64));
        tm = fmaxf(tm, __shfl_xor(tm, 32, 64));
        float mnew = fmaxf(m, tm);
        float scale = __expf(m - mnew);
        float ts = 0.f;
        #pragma unroll
        for (int n = 0; n < 4; ++n)
            #pragma unroll
            for (int r = 0; r < 4; ++r) {
                float p = __expf(acc[n][r] - mnew);
                acc[n][r] = p;
                ts += p;
            }
        ts += __shfl_xor(ts, 16, 64);
        ts += __shfl_xor(ts, 32, 64);
        l = l * scale + ts;
        m = mnew;
        #pragma unroll
        for (int n = 0; n < 4; ++n) o[n] = o[n] * scale;

        #pragma unroll
        for (int n = 0; n < 4; ++n) {
            bf16x4 pv;
            pv[0] = (__bf16)acc[n][0]; pv[1] = (__bf16)acc[n][1];
            pv[2] = (__bf16)acc[n][2]; pv[3] = (__bf16)acc[n][3];
            *(bf16x4*)&P_lds[wave][lq][16 * n + lg * 4] = pv;
        }
        bf16x8 bp0 = *(const bf16x8*)&P_lds[wave][lq][lg * 8];
        bf16x8 bp1 = *(const bf16x8*)&P_lds[wave][lq][32 + lg * 8];

        __builtin_amdgcn_s_setprio(1);
        #pragma unroll
        for (int n = 0; n < 4; ++n) {
            bf16x8 vf0 = *(const bf16x8*)&Vs[fidx[n]];
            bf16x8 vf1 = *(const bf16x8*)&Vs[fidx[n] ^ 32];
            o[n] = __builtin_amdgcn_mfma_f32_16x16x32_bf16(vf0, bp0, o[n], 0, 0, 0);
            o[n] = __builtin_amdgcn_mfma_f32_16x16x32_bf16(vf1, bp1, o[n], 0, 0, 0);
        }
        __builtin_amdgcn_s_setprio(0);
    }

    float g = gi / l;
    #pragma unroll
    for (int n = 0; n < 4; ++n) {
        bf16x4 ov;
        ov[0] = (__bf16)(o[n][0] * g); ov[1] = (__bf16)(o[n][1] * g);
        ov[2] = (__bf16)(o[n][2] * g); ov[3] = (__bf16)(o[n][3] * g);
        *(bf16x4*)(ao + (((size_t)b * SS + i) * HH + h) * DD + 16 * n + lg * 4) = ov;
    }
}

// ------------------------------------------------------------------
extern "C" void kernel_launch(void* const* d_in, const int* in_sizes, int n_in,
                              void* d_out, int out_size, void* d_ws, size_t ws_size,
                              hipStream_t stream)
{
    const float* tokens = (const float*)d_in[0];
    const float* vres   = (const float*)d_in[1];
    const int*   ep     = (const int*)d_in[2];
    const float* Wq     = (const float*)d_in[3];
    const float* Wkv    = (const float*)d_in[4];
    const float* Wo     = (const float*)d_in[5];
    const float* Wg     = (const float*)d_in[6];
    const float* Wmix   = (const float*)d_in[7];
    float* out = (float*)d_out;

    char* wsb = (char*)d_ws;
    unsigned short* qbh  = (unsigned short*)(wsb + 0);         // 8 MB
    unsigned short* kbh  = (unsigned short*)(wsb + 8388608);   // 8 MB
    unsigned short* vb0  = (unsigned short*)(wsb + 16777216);  // 8 MB
    unsigned short* vtb  = (unsigned short*)(wsb + 25165824);  // 8 MB
    unsigned short* aob  = (unsigned short*)(wsb + 33554432);  // 8 MB
    unsigned short* tokA = (unsigned short*)(wsb + 41943040);  // 8 MB
    unsigned short* BtW  = (unsigned short*)(wsb + 50331648);  // 6 MB
    float* gatep = (float*)(wsb + 56623104);                   // 256 KB
    float* mixp  = (float*)(wsb + 56885248);                   // 256 KB
    int*   epst  = (int*)(wsb + 57147392);                     // 16 KB
    unsigned short* wgmt = (unsigned short*)(wsb + 57163776);  // 64 KB
    unsigned short* WotW = (unsigned short*)(wsb + 57229312);  // 2 MB

    prep_all_kernel<<<6288, 256, 0, stream>>>(tokens, tokA, Wq, Wkv, Wo, BtW, WotW,
                                              Wg, Wmix, wgmt, ep, epst);
    projmix_kernel<<<1024, 256, 0, stream>>>(tokA, BtW, qbh, kbh, vb0,
                                             wgmt, gatep, mixp);
    vlerp_t_kernel<<<dim3(SS / 64, BB * HH), 256, 0, stream>>>(vb0, vres, mixp, vtb);
    attn_mfma<<<512, 512, 0, stream>>>(qbh, kbh, vtb, epst, gatep, aob);

    gemm_mfma<128, 64><<<dim3(16, 32), 256, 0, stream>>>(aob, WotW, out);
}

// Round 16
// 110.808 us; speedup vs baseline: 1.1217x; 1.1217x over previous
//
#include <hip/hip_runtime.h>
#include <math.h>

#define BB 2
#define SS 2048
#define DIMM 1024
#define HH 16
#define DD 64
#define WINDOW 512

typedef __bf16 bf16x8 __attribute__((ext_vector_type(8)));
typedef __bf16 bf16x4 __attribute__((ext_vector_type(4)));
typedef float f32x4 __attribute__((ext_vector_type(4)));

__device__ __forceinline__ unsigned short f2bf(float f) {
    unsigned int u = __float_as_uint(f);
    u = (u + 0x7FFFu + ((u >> 16) & 1u)) >> 16;
    return (unsigned short)u;
}
__device__ __forceinline__ float bf2f(unsigned short u) {
    return __uint_as_float((unsigned int)u << 16);
}

__device__ __forceinline__ void async_cp16(unsigned short* lds_dst, const unsigned short* g_src) {
    __builtin_amdgcn_global_load_lds(
        (const __attribute__((address_space(1))) unsigned int*)g_src,
        (__attribute__((address_space(3))) unsigned int*)lds_dst, 16, 0, 0);
}

// ------------------------------------------------------------------
// prep_all: weight transposes (blocks 0-4095), tokens->bf16
// (4096-6143), [Wg|Wmix] pack (6144-6271), epstart (6272-6287),
// RoPE cos/sin table (6288-6543): tab[s][p] = {cos,sin}(s * 10000^(-2p/64))
// ------------------------------------------------------------------
__global__ __launch_bounds__(256) void prep_all_kernel(
    const float* __restrict__ tokens, unsigned short* __restrict__ tokA,
    const float* __restrict__ Wq, const float* __restrict__ Wkv,
    const float* __restrict__ Wo, unsigned short* __restrict__ BtW,
    unsigned short* __restrict__ WotW,
    const float* __restrict__ Wg, const float* __restrict__ Wmix,
    unsigned short* __restrict__ wgmt,
    const int* __restrict__ ep, int* __restrict__ epstart,
    float2* __restrict__ ropetab)
{
    int bid = blockIdx.x;
    int tid = threadIdx.x;
    if (bid < 4096) {
        const float* src;
        unsigned short* dst;
        int C, bx, by;
        if (bid < 1024) {
            src = Wq; dst = BtW; C = 1024; bx = bid & 31; by = bid >> 5;
        } else if (bid < 3072) {
            int rel = bid - 1024;
            src = Wkv; dst = BtW + 1024 * 1024; C = 2048; bx = rel & 63; by = rel >> 6;
        } else {
            int rel = bid - 3072;
            src = Wo; dst = WotW; C = 1024; bx = rel & 31; by = rel >> 5;
        }
        const int R = 1024;
        __shared__ float t[32][33];
        int c0 = bx * 32, r0 = by * 32;
        int tx = tid & 31, ty = tid >> 5;
        #pragma unroll
        for (int u = 0; u < 4; ++u)
            t[ty + 8 * u][tx] = src[(size_t)(r0 + ty + 8 * u) * C + c0 + tx];
        __syncthreads();
        #pragma unroll
        for (int u = 0; u < 4; ++u)
            dst[(size_t)(c0 + ty + 8 * u) * R + r0 + tx] = f2bf(t[tx][ty + 8 * u]);
    } else if (bid < 6144) {
        const int n4 = (BB * SS * DIMM) / 4;
        for (int i = (bid - 4096) * 256 + tid; i < n4; i += 2048 * 256) {
            float4 v = ((const float4*)tokens)[i];
            ushort4 o;
            o.x = f2bf(v.x); o.y = f2bf(v.y); o.z = f2bf(v.z); o.w = f2bf(v.w);
            ((ushort4*)tokA)[i] = o;
        }
    } else if (bid < 6272) {
        int idx = (bid - 6144) * 256 + tid;
        int n = idx >> 10, k = idx & 1023;
        const float* src = (n < 16) ? Wg : Wmix;
        wgmt[idx] = f2bf(src[k * HH + (n & 15)]);
    } else if (bid < 6288) {
        int idx = (bid - 6272) * 256 + tid;
        int b = idx >> 11, i = idx & 2047;
        const int* e = ep + b * SS;
        int v = e[i];
        int lo = 0, hi = i;
        while (lo < hi) {
            int mid = (lo + hi) >> 1;
            if (e[mid] == v) hi = mid; else lo = mid + 1;
        }
        epstart[idx] = lo;
    } else {
        int idx = (bid - 6288) * 256 + tid;   // 0..65535
        int s = idx >> 5, p = idx & 31;
        float invf = powf(10000.f, -(float)(2 * p) * (1.f / 64.f));
        float ang = (float)s * invf;
        float rr = ang - 6.2831853f * floorf(ang * 0.15915494f);
        float cs, sn;
        __sincosf(rr, &sn, &cs);
        ropetab[idx] = make_float2(cs, sn);
    }
}

// ------------------------------------------------------------------
// projmix: blocks 0-767 = proj GEMM (128x128, 2-buffer, R6 structure,
// scatter epilogue -> bf16 q/k/v); blocks 768-1023 = mixgate MFMA.
// ------------------------------------------------------------------
__global__ __launch_bounds__(256) void projmix_kernel(
    const unsigned short* __restrict__ A, const unsigned short* __restrict__ Bt,
    unsigned short* __restrict__ qo, unsigned short* __restrict__ ko,
    unsigned short* __restrict__ vo,
    const unsigned short* __restrict__ wgmt,
    float* __restrict__ gate, float* __restrict__ mix)
{
    __shared__ unsigned short As[2][128 * 32];
    __shared__ unsigned short Bs[2][128 * 32];
    __shared__ float red[4][16][32];

    const int K = 1024;
    int bid = blockIdx.x;
    int tid = threadIdx.x;
    int lane = tid & 63;
    int wave = tid >> 6;
    int fr = lane & 15, hi = lane >> 4;

    if (bid < 768) {
        int nbase = (bid % 24) * 128;
        int mbase = (bid / 24) * 128;
        int wr = wave >> 1, wc = wave & 1;

        int srow = tid >> 2;
        int sp   = tid & 3;
        int scol = (sp ^ ((srow >> 1) & 3)) * 8;
        const unsigned short* agp0 = A  + (size_t)(mbase + srow) * K + scol;
        const unsigned short* agp1 = A  + (size_t)(mbase + srow + 64) * K + scol;
        const unsigned short* bgp0 = Bt + (size_t)(nbase + srow) * K + scol;
        const unsigned short* bgp1 = Bt + (size_t)(nbase + srow + 64) * K + scol;

        f32x4 acc[4][4];
        #pragma unroll
        for (int m_ = 0; m_ < 4; ++m_)
            #pragma unroll
            for (int n_ = 0; n_ < 4; ++n_)
                acc[m_][n_] = (f32x4){0.f, 0.f, 0.f, 0.f};

        int aidx[4], bidx[4];
        #pragma unroll
        for (int m_ = 0; m_ < 4; ++m_) {
            int row = wr * 64 + m_ * 16 + fr;
            aidx[m_] = row * 32 + (hi ^ ((row >> 1) & 3)) * 8;
        }
        #pragma unroll
        for (int n_ = 0; n_ < 4; ++n_) {
            int row = wc * 64 + n_ * 16 + fr;
            bidx[n_] = row * 32 + (hi ^ ((row >> 1) & 3)) * 8;
        }

        auto stage = [&](int buf, int k0) {
            async_cp16(&As[buf][tid * 8], agp0 + k0);
            async_cp16(&As[buf][2048 + tid * 8], agp1 + k0);
            async_cp16(&Bs[buf][tid * 8], bgp0 + k0);
            async_cp16(&Bs[buf][2048 + tid * 8], bgp1 + k0);
        };

        stage(0, 0);
        for (int k0 = 0; k0 < K; k0 += 32) {
            int cur = (k0 >> 5) & 1;
            __syncthreads();
            if (k0 + 32 < K) stage(cur ^ 1, k0 + 32);

            bf16x8 af[4], bfr[4];
            #pragma unroll
            for (int m_ = 0; m_ < 4; ++m_) af[m_] = *(const bf16x8*)&As[cur][aidx[m_]];
            #pragma unroll
            for (int n_ = 0; n_ < 4; ++n_) bfr[n_] = *(const bf16x8*)&Bs[cur][bidx[n_]];
            #pragma unroll
            for (int m_ = 0; m_ < 4; ++m_)
                #pragma unroll
                for (int n_ = 0; n_ < 4; ++n_)
                    acc[m_][n_] = __builtin_amdgcn_mfma_f32_16x16x32_bf16(
                        af[m_], bfr[n_], acc[m_][n_], 0, 0, 0);
        }

        #pragma unroll
        for (int m_ = 0; m_ < 4; ++m_) {
            #pragma unroll
            for (int n_ = 0; n_ < 4; ++n_) {
                int c = nbase + wc * 64 + n_ * 16 + fr;
                int cc = c & 1023, h = cc >> 6, d = cc & 63;
                unsigned short* dst = (c < 1024) ? qo : (c < 2048) ? ko : vo;
                #pragma unroll
                for (int j = 0; j < 4; ++j) {
                    int mg = mbase + wr * 64 + m_ * 16 + hi * 4 + j;
                    int b = mg >> 11, s = mg & 2047;
                    dst[(((size_t)b * HH + h) * SS + s) * DD + d] = f2bf(acc[m_][n_][j]);
                }
            }
        }
    } else {
        // mixgate: sigmoid(tokens_bf16 @ Wgm^T), 16 rows per block
        int mbase = (bid - 768) * 16;
        int kw = wave * 256;

        f32x4 acc[2];
        acc[0] = (f32x4){0.f, 0.f, 0.f, 0.f};
        acc[1] = (f32x4){0.f, 0.f, 0.f, 0.f};

        const unsigned short* a0 = A + (size_t)(mbase + fr) * 1024 + kw + hi * 8;
        const unsigned short* b0 = wgmt + (size_t)fr * 1024 + kw + hi * 8;
        const unsigned short* b1 = wgmt + (size_t)(16 + fr) * 1024 + kw + hi * 8;

        #pragma unroll 2
        for (int k = 0; k < 256; k += 32) {
            bf16x8 af0 = *(const bf16x8*)(a0 + k);
            bf16x8 bf0 = *(const bf16x8*)(b0 + k);
            bf16x8 bf1 = *(const bf16x8*)(b1 + k);
            acc[0] = __builtin_amdgcn_mfma_f32_16x16x32_bf16(af0, bf0, acc[0], 0, 0, 0);
            acc[1] = __builtin_amdgcn_mfma_f32_16x16x32_bf16(af0, bf1, acc[1], 0, 0, 0);
        }

        #pragma unroll
        for (int n_ = 0; n_ < 2; ++n_)
            #pragma unroll
            for (int j = 0; j < 4; ++j)
                red[wave][hi * 4 + j][n_ * 16 + fr] = acc[n_][j];
        __syncthreads();

        #pragma unroll
        for (int e = 0; e < 2; ++e) {
            int idx = tid * 2 + e;
            int r = idx >> 5, c = idx & 31;
            float s4 = red[0][r][c] + red[1][r][c] + red[2][r][c] + red[3][r][c];
            float sg = 1.f / (1.f + __expf(-s4));
            int mg = mbase + r;
            int b = mg >> 11, s = mg & 2047;
            int h = c & 15;
            float* dst = (c < 16) ? gate : mix;
            dst[((size_t)b * HH + h) * SS + s] = sg;
        }
    }
}

// ------------------------------------------------------------------
// bf16 MFMA GEMM (output GEMM), 2-buffer prefetch, R6 structure
// ------------------------------------------------------------------
template<int BM, int BN>
__global__ __launch_bounds__(256) void gemm_mfma(
    const unsigned short* __restrict__ A, const unsigned short* __restrict__ Bt,
    float* __restrict__ C)
{
    const int K = 1024;
    constexpr int MFR = BM / 32;
    constexpr int NFR = BN / 32;
    int nbase = blockIdx.x * BN;
    int mbase = blockIdx.y * BM;

    int tid = threadIdx.x;
    int lane = tid & 63;
    int wave = tid >> 6;
    int wr = wave >> 1, wc = wave & 1;
    int fr = lane & 15, hi = lane >> 4;

    __shared__ unsigned short As[2][BM * 32];
    __shared__ unsigned short Bs[2][BN * 32];

    int srow = tid >> 2;
    int sp   = tid & 3;
    int scol = (sp ^ ((srow >> 1) & 3)) * 8;
    const unsigned short* agp0 = A  + (size_t)(mbase + srow) * K + scol;
    const unsigned short* agp1 = (BM == 128)
        ? A + (size_t)(mbase + srow + 64) * K + scol : agp0;
    const unsigned short* bgp0 = Bt + (size_t)(nbase + srow) * K + scol;
    const unsigned short* bgp1 = (BN == 128)
        ? Bt + (size_t)(nbase + srow + 64) * K + scol : bgp0;

    f32x4 acc[MFR][NFR];
    #pragma unroll
    for (int m_ = 0; m_ < MFR; ++m_)
        #pragma unroll
        for (int n_ = 0; n_ < NFR; ++n_)
            acc[m_][n_] = (f32x4){0.f, 0.f, 0.f, 0.f};

    int aidx[MFR], bidx[NFR];
    #pragma unroll
    for (int m_ = 0; m_ < MFR; ++m_) {
        int row = wr * (BM / 2) + m_ * 16 + fr;
        aidx[m_] = row * 32 + (hi ^ ((row >> 1) & 3)) * 8;
    }
    #pragma unroll
    for (int n_ = 0; n_ < NFR; ++n_) {
        int row = wc * (BN / 2) + n_ * 16 + fr;
        bidx[n_] = row * 32 + (hi ^ ((row >> 1) & 3)) * 8;
    }

    auto stage = [&](int buf, int k0) {
        async_cp16(&As[buf][tid * 8], agp0 + k0);
        if constexpr (BM == 128)
            async_cp16(&As[buf][2048 + tid * 8], agp1 + k0);
        async_cp16(&Bs[buf][tid * 8], bgp0 + k0);
        if constexpr (BN == 128)
            async_cp16(&Bs[buf][2048 + tid * 8], bgp1 + k0);
    };

    stage(0, 0);
    for (int k0 = 0; k0 < K; k0 += 32) {
        int cur = (k0 >> 5) & 1;
        __syncthreads();
        if (k0 + 32 < K) stage(cur ^ 1, k0 + 32);

        bf16x8 af[MFR], bfr[NFR];
        #pragma unroll
        for (int m_ = 0; m_ < MFR; ++m_) af[m_] = *(const bf16x8*)&As[cur][aidx[m_]];
        #pragma unroll
        for (int n_ = 0; n_ < NFR; ++n_) bfr[n_] = *(const bf16x8*)&Bs[cur][bidx[n_]];
        #pragma unroll
        for (int m_ = 0; m_ < MFR; ++m_)
            #pragma unroll
            for (int n_ = 0; n_ < NFR; ++n_)
                acc[m_][n_] = __builtin_amdgcn_mfma_f32_16x16x32_bf16(
                    af[m_], bfr[n_], acc[m_][n_], 0, 0, 0);
    }

    #pragma unroll
    for (int m_ = 0; m_ < MFR; ++m_) {
        #pragma unroll
        for (int n_ = 0; n_ < NFR; ++n_) {
            int c = nbase + wc * (BN / 2) + n_ * 16 + fr;
            #pragma unroll
            for (int j = 0; j < 4; ++j) {
                int mg = mbase + wr * (BM / 2) + m_ * 16 + hi * 4 + j;
                C[(size_t)mg * 1024 + c] = acc[m_][n_][j];
            }
        }
    }
}

// ------------------------------------------------------------------
// RoPE in-place on bf16 q,k (table-driven); V lerp -> V^T bf16 [bh][d][s]
// ------------------------------------------------------------------
__global__ __launch_bounds__(256) void rope_lerp_kernel(
    unsigned short* __restrict__ q, unsigned short* __restrict__ k,
    const unsigned short* __restrict__ v0, const float* __restrict__ vres,
    const float* __restrict__ mix, unsigned short* __restrict__ vt,
    const float2* __restrict__ ropetab)
{
    int st = blockIdx.x;
    int bh = blockIdx.y;
    int tid = threadIdx.x;
    int sl = tid >> 2;
    int dg = (tid & 3) * 16;
    int s = st * 64 + sl;
    size_t rowoff = ((size_t)bh * SS + s) * DD + dg;

    __shared__ unsigned short vtile[64][66];

    union { uint4 v[2]; unsigned short u[16]; } qa, ka, va;
    qa.v[0] = *(const uint4*)(q + rowoff);
    qa.v[1] = *(const uint4*)(q + rowoff + 8);
    ka.v[0] = *(const uint4*)(k + rowoff);
    ka.v[1] = *(const uint4*)(k + rowoff + 8);
    va.v[0] = *(const uint4*)(v0 + rowoff);
    va.v[1] = *(const uint4*)(v0 + rowoff + 8);
    float4 w[4];
    #pragma unroll
    for (int u = 0; u < 4; ++u) w[u] = *(const float4*)(vres + rowoff + 4 * u);
    float mx = mix[(size_t)bh * SS + s];
    const float2* tb = ropetab + (size_t)s * 32 + (dg >> 1);

    #pragma unroll
    for (int u = 0; u < 8; ++u) {
        float2 cssn = tb[u];
        float cs = cssn.x, sn = cssn.y;
        float x = bf2f(qa.u[2 * u]), y = bf2f(qa.u[2 * u + 1]);
        qa.u[2 * u]     = f2bf((x * cs - y * sn) * 0.125f);
        qa.u[2 * u + 1] = f2bf((y * cs + x * sn) * 0.125f);
        x = bf2f(ka.u[2 * u]); y = bf2f(ka.u[2 * u + 1]);
        ka.u[2 * u]     = f2bf(x * cs - y * sn);
        ka.u[2 * u + 1] = f2bf(y * cs + x * sn);
    }
    *(uint4*)(q + rowoff)     = qa.v[0];
    *(uint4*)(q + rowoff + 8) = qa.v[1];
    *(uint4*)(k + rowoff)     = ka.v[0];
    *(uint4*)(k + rowoff + 8) = ka.v[1];

    #pragma unroll
    for (int e = 0; e < 16; ++e) {
        float vv = bf2f(va.u[e]);
        float wr = ((const float*)w)[e];
        vtile[sl][dg + e] = f2bf(vv + mx * (wr - vv));
    }
    __syncthreads();

    int d = tid >> 2;
    int sseg = (tid & 3) * 16;
    union { uint4 v[2]; unsigned short u[16]; } ot;
    #pragma unroll
    for (int e = 0; e < 16; ++e) ot.u[e] = vtile[sseg + e][d];
    unsigned short* dst = vt + ((size_t)bh * DD + d) * SS + st * 64 + sseg;
    *(uint4*)dst = ot.v[0];
    *(uint4*)(dst + 8) = ot.v[1];
}

// ------------------------------------------------------------------
// MFMA flash attention: 8 waves x 16 queries (128-q tile), KVBLK=64,
// single-buffer LDS staging, XCD-swizzled grid of 512
// ------------------------------------------------------------------
__global__ __launch_bounds__(512) void attn_mfma(
    const unsigned short* __restrict__ qbh, const unsigned short* __restrict__ kbh,
    const unsigned short* __restrict__ vt, const int* __restrict__ epstart,
    const float* __restrict__ gate, unsigned short* __restrict__ ao)
{
    int orig = blockIdx.x;
    int swz  = (orig & 7) * 64 + (orig >> 3);
    int bh = swz >> 4, qt = swz & 15;
    int b = bh >> 4, h = bh & 15;
    int q0 = qt * 128;
    int tid = threadIdx.x;
    int wave = tid >> 6, lane = tid & 63;
    int lq = lane & 15, lg = lane >> 4;
    int i = q0 + wave * 16 + lq;

    __shared__ unsigned short Ks[4096];
    __shared__ unsigned short Vs[4096];
    alignas(16) __shared__ unsigned short P_lds[8][16][72];

    int srow = tid >> 3;
    int sc = (((tid & 7) ^ (srow & 7)) << 3);
    const unsigned short* kS = kbh + ((size_t)bh * SS + srow) * DD + sc;
    const unsigned short* vS = vt + ((size_t)bh * DD + srow) * SS + sc;

    int fidx[4];
    #pragma unroll
    for (int n = 0; n < 4; ++n) {
        int r = 16 * n + lq;
        fidx[n] = r * 64 + ((lg ^ (r & 7)) << 3);
    }

    const unsigned short* qrow = qbh + ((size_t)bh * SS + i) * DD + lg * 8;
    bf16x8 bq0 = *(const bf16x8*)qrow;
    bf16x8 bq1 = *(const bf16x8*)(qrow + 32);

    int jmin = i - WINDOW;
    int es = epstart[b * SS + i];
    if (es > jmin) jmin = es;
    float gi = gate[(size_t)bh * SS + i];

    float m = -1e30f, l = 0.f;
    f32x4 o[4];
    #pragma unroll
    for (int n = 0; n < 4; ++n) o[n] = (f32x4){0.f, 0.f, 0.f, 0.f};

    int jt0 = (q0 >= 512) ? ((q0 - 512) >> 6) : 0;
    int jt1 = (q0 + 127) >> 6;
    int nt = jt1 - jt0 + 1;
    int jb0 = jt0 * 64;

    for (int u = 0; u < nt; ++u) {
        int jbase = jb0 + 64 * u;

        __syncthreads();
        async_cp16(&Ks[tid * 8], kS + (size_t)jbase * DD);
        async_cp16(&Vs[tid * 8], vS + jbase);
        __syncthreads();

        f32x4 acc[4];
        #pragma unroll
        for (int n = 0; n < 4; ++n) acc[n] = (f32x4){0.f, 0.f, 0.f, 0.f};
        __builtin_amdgcn_s_setprio(1);
        #pragma unroll
        for (int n = 0; n < 4; ++n) {
            bf16x8 kf0 = *(const bf16x8*)&Ks[fidx[n]];
            bf16x8 kf1 = *(const bf16x8*)&Ks[fidx[n] ^ 32];
            acc[n] = __builtin_amdgcn_mfma_f32_16x16x32_bf16(kf0, bq0, acc[n], 0, 0, 0);
            acc[n] = __builtin_amdgcn_mfma_f32_16x16x32_bf16(kf1, bq1, acc[n], 0, 0, 0);
        }
        __builtin_amdgcn_s_setprio(0);

        int jb = jbase + lg * 4;
        #pragma unroll
        for (int n = 0; n < 4; ++n)
            #pragma unroll
            for (int r = 0; r < 4; ++r) {
                int j = jb + 16 * n + r;
                if (j < jmin || j > i) acc[n][r] = -3e38f;
            }

        float tm = -3e38f;
        #pragma unroll
        for (int n = 0; n < 4; ++n)
            tm = fmaxf(tm, fmaxf(fmaxf(acc[n][0], acc[n][1]), fmaxf(acc[n][2], acc[n][3])));
        tm = fmaxf(tm, __shfl_xor(tm, 16, 64));
        tm = fmaxf(tm, __shfl_xor(tm, 32, 64));
        float mnew = fmaxf(m, tm);
        float scale = __expf(m - mnew);
        float ts = 0.f;
        #pragma unroll
        for (int n = 0; n < 4; ++n)
            #pragma unroll
            for (int r = 0; r < 4; ++r) {
                float p = __expf(acc[n][r] - mnew);
                acc[n][r] = p;
                ts += p;
            }
        ts += __shfl_xor(ts, 16, 64);
        ts += __shfl_xor(ts, 32, 64);
        l = l * scale + ts;
        m = mnew;
        #pragma unroll
        for (int n = 0; n < 4; ++n) o[n] = o[n] * scale;

        #pragma unroll
        for (int n = 0; n < 4; ++n) {
            bf16x4 pv;
            pv[0] = (__bf16)acc[n][0]; pv[1] = (__bf16)acc[n][1];
            pv[2] = (__bf16)acc[n][2]; pv[3] = (__bf16)acc[n][3];
            *(bf16x4*)&P_lds[wave][lq][16 * n + lg * 4] = pv;
        }
        bf16x8 bp0 = *(const bf16x8*)&P_lds[wave][lq][lg * 8];
        bf16x8 bp1 = *(const bf16x8*)&P_lds[wave][lq][32 + lg * 8];

        __builtin_amdgcn_s_setprio(1);
        #pragma unroll
        for (int n = 0; n < 4; ++n) {
            bf16x8 vf0 = *(const bf16x8*)&Vs[fidx[n]];
            bf16x8 vf1 = *(const bf16x8*)&Vs[fidx[n] ^ 32];
            o[n] = __builtin_amdgcn_mfma_f32_16x16x32_bf16(vf0, bp0, o[n], 0, 0, 0);
            o[n] = __builtin_amdgcn_mfma_f32_16x16x32_bf16(vf1, bp1, o[n], 0, 0, 0);
        }
        __builtin_amdgcn_s_setprio(0);
    }

    float g = gi / l;
    #pragma unroll
    for (int n = 0; n < 4; ++n) {
        bf16x4 ov;
        ov[0] = (__bf16)(o[n][0] * g); ov[1] = (__bf16)(o[n][1] * g);
        ov[2] = (__bf16)(o[n][2] * g); ov[3] = (__bf16)(o[n][3] * g);
        *(bf16x4*)(ao + (((size_t)b * SS + i) * HH + h) * DD + 16 * n + lg * 4) = ov;
    }
}

// ------------------------------------------------------------------
extern "C" void kernel_launch(void* const* d_in, const int* in_sizes, int n_in,
                              void* d_out, int out_size, void* d_ws, size_t ws_size,
                              hipStream_t stream)
{
    const float* tokens = (const float*)d_in[0];
    const float* vres   = (const float*)d_in[1];
    const int*   ep     = (const int*)d_in[2];
    const float* Wq     = (const float*)d_in[3];
    const float* Wkv    = (const float*)d_in[4];
    const float* Wo     = (const float*)d_in[5];
    const float* Wg     = (const float*)d_in[6];
    const float* Wmix   = (const float*)d_in[7];
    float* out = (float*)d_out;

    char* wsb = (char*)d_ws;
    unsigned short* qbh  = (unsigned short*)(wsb + 0);         // 8 MB
    unsigned short* kbh  = (unsigned short*)(wsb + 8388608);   // 8 MB
    unsigned short* vb0  = (unsigned short*)(wsb + 16777216);  // 8 MB
    unsigned short* vtb  = (unsigned short*)(wsb + 25165824);  // 8 MB
    unsigned short* aob  = (unsigned short*)(wsb + 33554432);  // 8 MB
    unsigned short* tokA = (unsigned short*)(wsb + 41943040);  // 8 MB
    unsigned short* BtW  = (unsigned short*)(wsb + 50331648);  // 6 MB
    float* gatep = (float*)(wsb + 56623104);                   // 256 KB
    float* mixp  = (float*)(wsb + 56885248);                   // 256 KB
    int*   epst  = (int*)(wsb + 57147392);                     // 16 KB
    unsigned short* wgmt = (unsigned short*)(wsb + 57163776);  // 64 KB
    unsigned short* WotW = (unsigned short*)(wsb + 57229312);  // 2 MB
    float2* ropetab = (float2*)(wsb + 59326464);               // 512 KB

    prep_all_kernel<<<6544, 256, 0, stream>>>(tokens, tokA, Wq, Wkv, Wo, BtW, WotW,
                                              Wg, Wmix, wgmt, ep, epst, ropetab);
    projmix_kernel<<<1024, 256, 0, stream>>>(tokA, BtW, qbh, kbh, vb0,
                                             wgmt, gatep, mixp);
    rope_lerp_kernel<<<dim3(SS / 64, BB * HH), 256, 0, stream>>>(qbh, kbh, vb0, vres, mixp, vtb, ropetab);
    attn_mfma<<<512, 512, 0, stream>>>(qbh, kbh, vtb, epst, gatep, aob);

    gemm_mfma<128, 64><<<dim3(16, 32), 256, 0, stream>>>(aob, WotW, out);
}

// Round 17
// 110.680 us; speedup vs baseline: 1.1230x; 1.0012x over previous
//
#include <hip/hip_runtime.h>
#include <math.h>

#define BB 2
#define SS 2048
#define DIMM 1024
#define HH 16
#define DD 64
#define WINDOW 512

typedef __bf16 bf16x8 __attribute__((ext_vector_type(8)));
typedef __bf16 bf16x4 __attribute__((ext_vector_type(4)));
typedef float f32x4 __attribute__((ext_vector_type(4)));

__device__ __forceinline__ unsigned short f2bf(float f) {
    unsigned int u = __float_as_uint(f);
    u = (u + 0x7FFFu + ((u >> 16) & 1u)) >> 16;
    return (unsigned short)u;
}
__device__ __forceinline__ float bf2f(unsigned short u) {
    return __uint_as_float((unsigned int)u << 16);
}

__device__ __forceinline__ void async_cp16(unsigned short* lds_dst, const unsigned short* g_src) {
    __builtin_amdgcn_global_load_lds(
        (const __attribute__((address_space(1))) unsigned int*)g_src,
        (__attribute__((address_space(3))) unsigned int*)lds_dst, 16, 0, 0);
}

// ------------------------------------------------------------------
// prep_all: weight transposes (blocks 0-4095), tokens->bf16
// (4096-6143), [Wg|Wmix] pack (6144-6271), epstart (6272-6287),
// RoPE cos/sin table (6288-6543): tab[s][p] = {cos,sin}(s * 10000^(-2p/64))
// ------------------------------------------------------------------
__global__ __launch_bounds__(256) void prep_all_kernel(
    const float* __restrict__ tokens, unsigned short* __restrict__ tokA,
    const float* __restrict__ Wq, const float* __restrict__ Wkv,
    const float* __restrict__ Wo, unsigned short* __restrict__ BtW,
    unsigned short* __restrict__ WotW,
    const float* __restrict__ Wg, const float* __restrict__ Wmix,
    unsigned short* __restrict__ wgmt,
    const int* __restrict__ ep, int* __restrict__ epstart,
    float2* __restrict__ ropetab)
{
    int bid = blockIdx.x;
    int tid = threadIdx.x;
    if (bid < 4096) {
        const float* src;
        unsigned short* dst;
        int C, bx, by;
        if (bid < 1024) {
            src = Wq; dst = BtW; C = 1024; bx = bid & 31; by = bid >> 5;
        } else if (bid < 3072) {
            int rel = bid - 1024;
            src = Wkv; dst = BtW + 1024 * 1024; C = 2048; bx = rel & 63; by = rel >> 6;
        } else {
            int rel = bid - 3072;
            src = Wo; dst = WotW; C = 1024; bx = rel & 31; by = rel >> 5;
        }
        const int R = 1024;
        __shared__ float t[32][33];
        int c0 = bx * 32, r0 = by * 32;
        int tx = tid & 31, ty = tid >> 5;
        #pragma unroll
        for (int u = 0; u < 4; ++u)
            t[ty + 8 * u][tx] = src[(size_t)(r0 + ty + 8 * u) * C + c0 + tx];
        __syncthreads();
        #pragma unroll
        for (int u = 0; u < 4; ++u)
            dst[(size_t)(c0 + ty + 8 * u) * R + r0 + tx] = f2bf(t[tx][ty + 8 * u]);
    } else if (bid < 6144) {
        const int n4 = (BB * SS * DIMM) / 4;
        for (int i = (bid - 4096) * 256 + tid; i < n4; i += 2048 * 256) {
            float4 v = ((const float4*)tokens)[i];
            ushort4 o;
            o.x = f2bf(v.x); o.y = f2bf(v.y); o.z = f2bf(v.z); o.w = f2bf(v.w);
            ((ushort4*)tokA)[i] = o;
        }
    } else if (bid < 6272) {
        int idx = (bid - 6144) * 256 + tid;
        int n = idx >> 10, k = idx & 1023;
        const float* src = (n < 16) ? Wg : Wmix;
        wgmt[idx] = f2bf(src[k * HH + (n & 15)]);
    } else if (bid < 6288) {
        int idx = (bid - 6272) * 256 + tid;
        int b = idx >> 11, i = idx & 2047;
        const int* e = ep + b * SS;
        int v = e[i];
        int lo = 0, hi = i;
        while (lo < hi) {
            int mid = (lo + hi) >> 1;
            if (e[mid] == v) hi = mid; else lo = mid + 1;
        }
        epstart[idx] = lo;
    } else {
        int idx = (bid - 6288) * 256 + tid;   // 0..65535
        int s = idx >> 5, p = idx & 31;
        float invf = powf(10000.f, -(float)(2 * p) * (1.f / 64.f));
        float ang = (float)s * invf;
        float rr = ang - 6.2831853f * floorf(ang * 0.15915494f);
        float cs, sn;
        __sincosf(rr, &sn, &cs);
        ropetab[idx] = make_float2(cs, sn);
    }
}

// ------------------------------------------------------------------
// projmix: blocks 0-767 = proj GEMM (128x128, 2-buffer, R6 structure,
// scatter epilogue -> bf16 q/k/v); blocks 768-1023 = mixgate MFMA.
// LDS overlaid via byte arena: GEMM uses 32 KB (As+Bs); mixgate's
// red[] aliases the same space (branches are block-disjoint).
// ------------------------------------------------------------------
__global__ __launch_bounds__(256) void projmix_kernel(
    const unsigned short* __restrict__ A, const unsigned short* __restrict__ Bt,
    unsigned short* __restrict__ qo, unsigned short* __restrict__ ko,
    unsigned short* __restrict__ vo,
    const unsigned short* __restrict__ wgmt,
    float* __restrict__ gate, float* __restrict__ mix)
{
    __shared__ char smem[32768];
    unsigned short* As = (unsigned short*)smem;            // 2 x 128*32
    unsigned short* Bs = (unsigned short*)(smem + 16384);  // 2 x 128*32
    float (*red)[16][32] = (float (*)[16][32])smem;        // mixgate alias (8 KB)

    const int K = 1024;
    int bid = blockIdx.x;
    int tid = threadIdx.x;
    int lane = tid & 63;
    int wave = tid >> 6;
    int fr = lane & 15, hi = lane >> 4;

    if (bid < 768) {
        int nbase = (bid % 24) * 128;
        int mbase = (bid / 24) * 128;
        int wr = wave >> 1, wc = wave & 1;

        int srow = tid >> 2;
        int sp   = tid & 3;
        int scol = (sp ^ ((srow >> 1) & 3)) * 8;
        const unsigned short* agp0 = A  + (size_t)(mbase + srow) * K + scol;
        const unsigned short* agp1 = A  + (size_t)(mbase + srow + 64) * K + scol;
        const unsigned short* bgp0 = Bt + (size_t)(nbase + srow) * K + scol;
        const unsigned short* bgp1 = Bt + (size_t)(nbase + srow + 64) * K + scol;

        f32x4 acc[4][4];
        #pragma unroll
        for (int m_ = 0; m_ < 4; ++m_)
            #pragma unroll
            for (int n_ = 0; n_ < 4; ++n_)
                acc[m_][n_] = (f32x4){0.f, 0.f, 0.f, 0.f};

        int aidx[4], bidx[4];
        #pragma unroll
        for (int m_ = 0; m_ < 4; ++m_) {
            int row = wr * 64 + m_ * 16 + fr;
            aidx[m_] = row * 32 + (hi ^ ((row >> 1) & 3)) * 8;
        }
        #pragma unroll
        for (int n_ = 0; n_ < 4; ++n_) {
            int row = wc * 64 + n_ * 16 + fr;
            bidx[n_] = row * 32 + (hi ^ ((row >> 1) & 3)) * 8;
        }

        auto stage = [&](int buf, int k0) {
            async_cp16(&As[buf * 4096 + tid * 8], agp0 + k0);
            async_cp16(&As[buf * 4096 + 2048 + tid * 8], agp1 + k0);
            async_cp16(&Bs[buf * 4096 + tid * 8], bgp0 + k0);
            async_cp16(&Bs[buf * 4096 + 2048 + tid * 8], bgp1 + k0);
        };

        stage(0, 0);
        for (int k0 = 0; k0 < K; k0 += 32) {
            int cur = (k0 >> 5) & 1;
            __syncthreads();
            if (k0 + 32 < K) stage(cur ^ 1, k0 + 32);

            bf16x8 af[4], bfr[4];
            #pragma unroll
            for (int m_ = 0; m_ < 4; ++m_) af[m_] = *(const bf16x8*)&As[cur * 4096 + aidx[m_]];
            #pragma unroll
            for (int n_ = 0; n_ < 4; ++n_) bfr[n_] = *(const bf16x8*)&Bs[cur * 4096 + bidx[n_]];
            #pragma unroll
            for (int m_ = 0; m_ < 4; ++m_)
                #pragma unroll
                for (int n_ = 0; n_ < 4; ++n_)
                    acc[m_][n_] = __builtin_amdgcn_mfma_f32_16x16x32_bf16(
                        af[m_], bfr[n_], acc[m_][n_], 0, 0, 0);
        }

        #pragma unroll
        for (int m_ = 0; m_ < 4; ++m_) {
            #pragma unroll
            for (int n_ = 0; n_ < 4; ++n_) {
                int c = nbase + wc * 64 + n_ * 16 + fr;
                int cc = c & 1023, h = cc >> 6, d = cc & 63;
                unsigned short* dst = (c < 1024) ? qo : (c < 2048) ? ko : vo;
                #pragma unroll
                for (int j = 0; j < 4; ++j) {
                    int mg = mbase + wr * 64 + m_ * 16 + hi * 4 + j;
                    int b = mg >> 11, s = mg & 2047;
                    dst[(((size_t)b * HH + h) * SS + s) * DD + d] = f2bf(acc[m_][n_][j]);
                }
            }
        }
    } else {
        // mixgate: sigmoid(tokens_bf16 @ Wgm^T), 16 rows per block
        int mbase = (bid - 768) * 16;
        int kw = wave * 256;

        f32x4 acc[2];
        acc[0] = (f32x4){0.f, 0.f, 0.f, 0.f};
        acc[1] = (f32x4){0.f, 0.f, 0.f, 0.f};

        const unsigned short* a0 = A + (size_t)(mbase + fr) * 1024 + kw + hi * 8;
        const unsigned short* b0 = wgmt + (size_t)fr * 1024 + kw + hi * 8;
        const unsigned short* b1 = wgmt + (size_t)(16 + fr) * 1024 + kw + hi * 8;

        #pragma unroll 2
        for (int k = 0; k < 256; k += 32) {
            bf16x8 af0 = *(const bf16x8*)(a0 + k);
            bf16x8 bf0 = *(const bf16x8*)(b0 + k);
            bf16x8 bf1 = *(const bf16x8*)(b1 + k);
            acc[0] = __builtin_amdgcn_mfma_f32_16x16x32_bf16(af0, bf0, acc[0], 0, 0, 0);
            acc[1] = __builtin_amdgcn_mfma_f32_16x16x32_bf16(af0, bf1, acc[1], 0, 0, 0);
        }

        #pragma unroll
        for (int n_ = 0; n_ < 2; ++n_)
            #pragma unroll
            for (int j = 0; j < 4; ++j)
                red[wave][hi * 4 + j][n_ * 16 + fr] = acc[n_][j];
        __syncthreads();

        #pragma unroll
        for (int e = 0; e < 2; ++e) {
            int idx = tid * 2 + e;
            int r = idx >> 5, c = idx & 31;
            float s4 = red[0][r][c] + red[1][r][c] + red[2][r][c] + red[3][r][c];
            float sg = 1.f / (1.f + __expf(-s4));
            int mg = mbase + r;
            int b = mg >> 11, s = mg & 2047;
            int h = c & 15;
            float* dst = (c < 16) ? gate : mix;
            dst[((size_t)b * HH + h) * SS + s] = sg;
        }
    }
}

// ------------------------------------------------------------------
// bf16 MFMA GEMM (output GEMM), 2-buffer prefetch, R6 structure
// ------------------------------------------------------------------
template<int BM, int BN>
__global__ __launch_bounds__(256) void gemm_mfma(
    const unsigned short* __restrict__ A, const unsigned short* __restrict__ Bt,
    float* __restrict__ C)
{
    const int K = 1024;
    constexpr int MFR = BM / 32;
    constexpr int NFR = BN / 32;
    int nbase = blockIdx.x * BN;
    int mbase = blockIdx.y * BM;

    int tid = threadIdx.x;
    int lane = tid & 63;
    int wave = tid >> 6;
    int wr = wave >> 1, wc = wave & 1;
    int fr = lane & 15, hi = lane >> 4;

    __shared__ unsigned short As[2][BM * 32];
    __shared__ unsigned short Bs[2][BN * 32];

    int srow = tid >> 2;
    int sp   = tid & 3;
    int scol = (sp ^ ((srow >> 1) & 3)) * 8;
    const unsigned short* agp0 = A  + (size_t)(mbase + srow) * K + scol;
    const unsigned short* agp1 = (BM == 128)
        ? A + (size_t)(mbase + srow + 64) * K + scol : agp0;
    const unsigned short* bgp0 = Bt + (size_t)(nbase + srow) * K + scol;
    const unsigned short* bgp1 = (BN == 128)
        ? Bt + (size_t)(nbase + srow + 64) * K + scol : bgp0;

    f32x4 acc[MFR][NFR];
    #pragma unroll
    for (int m_ = 0; m_ < MFR; ++m_)
        #pragma unroll
        for (int n_ = 0; n_ < NFR; ++n_)
            acc[m_][n_] = (f32x4){0.f, 0.f, 0.f, 0.f};

    int aidx[MFR], bidx[NFR];
    #pragma unroll
    for (int m_ = 0; m_ < MFR; ++m_) {
        int row = wr * (BM / 2) + m_ * 16 + fr;
        aidx[m_] = row * 32 + (hi ^ ((row >> 1) & 3)) * 8;
    }
    #pragma unroll
    for (int n_ = 0; n_ < NFR; ++n_) {
        int row = wc * (BN / 2) + n_ * 16 + fr;
        bidx[n_] = row * 32 + (hi ^ ((row >> 1) & 3)) * 8;
    }

    auto stage = [&](int buf, int k0) {
        async_cp16(&As[buf][tid * 8], agp0 + k0);
        if constexpr (BM == 128)
            async_cp16(&As[buf][2048 + tid * 8], agp1 + k0);
        async_cp16(&Bs[buf][tid * 8], bgp0 + k0);
        if constexpr (BN == 128)
            async_cp16(&Bs[buf][2048 + tid * 8], bgp1 + k0);
    };

    stage(0, 0);
    for (int k0 = 0; k0 < K; k0 += 32) {
        int cur = (k0 >> 5) & 1;
        __syncthreads();
        if (k0 + 32 < K) stage(cur ^ 1, k0 + 32);

        bf16x8 af[MFR], bfr[NFR];
        #pragma unroll
        for (int m_ = 0; m_ < MFR; ++m_) af[m_] = *(const bf16x8*)&As[cur][aidx[m_]];
        #pragma unroll
        for (int n_ = 0; n_ < NFR; ++n_) bfr[n_] = *(const bf16x8*)&Bs[cur][bidx[n_]];
        #pragma unroll
        for (int m_ = 0; m_ < MFR; ++m_)
            #pragma unroll
            for (int n_ = 0; n_ < NFR; ++n_)
                acc[m_][n_] = __builtin_amdgcn_mfma_f32_16x16x32_bf16(
                    af[m_], bfr[n_], acc[m_][n_], 0, 0, 0);
    }

    #pragma unroll
    for (int m_ = 0; m_ < MFR; ++m_) {
        #pragma unroll
        for (int n_ = 0; n_ < NFR; ++n_) {
            int c = nbase + wc * (BN / 2) + n_ * 16 + fr;
            #pragma unroll
            for (int j = 0; j < 4; ++j) {
                int mg = mbase + wr * (BM / 2) + m_ * 16 + hi * 4 + j;
                C[(size_t)mg * 1024 + c] = acc[m_][n_][j];
            }
        }
    }
}

// ------------------------------------------------------------------
// K RoPE in-place (table-driven); V lerp -> V^T bf16 [bh][d][s]
// (Q RoPE is applied inside attn at fragment load.)
// ------------------------------------------------------------------
__global__ __launch_bounds__(256) void rope_lerp_kernel(
    unsigned short* __restrict__ k,
    const unsigned short* __restrict__ v0, const float* __restrict__ vres,
    const float* __restrict__ mix, unsigned short* __restrict__ vt,
    const float2* __restrict__ ropetab)
{
    int st = blockIdx.x;
    int bh = blockIdx.y;
    int tid = threadIdx.x;
    int sl = tid >> 2;
    int dg = (tid & 3) * 16;
    int s = st * 64 + sl;
    size_t rowoff = ((size_t)bh * SS + s) * DD + dg;

    __shared__ unsigned short vtile[64][66];

    union { uint4 v[2]; unsigned short u[16]; } ka, va;
    ka.v[0] = *(const uint4*)(k + rowoff);
    ka.v[1] = *(const uint4*)(k + rowoff + 8);
    va.v[0] = *(const uint4*)(v0 + rowoff);
    va.v[1] = *(const uint4*)(v0 + rowoff + 8);
    float4 w[4];
    #pragma unroll
    for (int u = 0; u < 4; ++u) w[u] = *(const float4*)(vres + rowoff + 4 * u);
    float mx = mix[(size_t)bh * SS + s];
    const float2* tb = ropetab + (size_t)s * 32 + (dg >> 1);

    #pragma unroll
    for (int u = 0; u < 8; ++u) {
        float2 cssn = tb[u];
        float cs = cssn.x, sn = cssn.y;
        float x = bf2f(ka.u[2 * u]), y = bf2f(ka.u[2 * u + 1]);
        ka.u[2 * u]     = f2bf(x * cs - y * sn);
        ka.u[2 * u + 1] = f2bf(y * cs + x * sn);
    }
    *(uint4*)(k + rowoff)     = ka.v[0];
    *(uint4*)(k + rowoff + 8) = ka.v[1];

    #pragma unroll
    for (int e = 0; e < 16; ++e) {
        float vv = bf2f(va.u[e]);
        float wr = ((const float*)w)[e];
        vtile[sl][dg + e] = f2bf(vv + mx * (wr - vv));
    }
    __syncthreads();

    int d = tid >> 2;
    int sseg = (tid & 3) * 16;
    union { uint4 v[2]; unsigned short u[16]; } ot;
    #pragma unroll
    for (int e = 0; e < 16; ++e) ot.u[e] = vtile[sseg + e][d];
    unsigned short* dst = vt + ((size_t)bh * DD + d) * SS + st * 64 + sseg;
    *(uint4*)dst = ot.v[0];
    *(uint4*)(dst + 8) = ot.v[1];
}

// ------------------------------------------------------------------
// MFMA flash attention: 8 waves x 16 queries (128-q tile), KVBLK=64,
// single-buffer LDS staging, XCD-swizzled grid of 512.
// Q is RoPE'd in-register at load (pairs are lane-local); 0.125 folded.
// ------------------------------------------------------------------
__global__ __launch_bounds__(512) void attn_mfma(
    const unsigned short* __restrict__ qbh, const unsigned short* __restrict__ kbh,
    const unsigned short* __restrict__ vt, const int* __restrict__ epstart,
    const float* __restrict__ gate, unsigned short* __restrict__ ao,
    const float2* __restrict__ ropetab)
{
    int orig = blockIdx.x;
    int swz  = (orig & 7) * 64 + (orig >> 3);
    int bh = swz >> 4, qt = swz & 15;
    int b = bh >> 4, h = bh & 15;
    int q0 = qt * 128;
    int tid = threadIdx.x;
    int wave = tid >> 6, lane = tid & 63;
    int lq = lane & 15, lg = lane >> 4;
    int i = q0 + wave * 16 + lq;

    __shared__ unsigned short Ks[4096];
    __shared__ unsigned short Vs[4096];
    alignas(16) __shared__ unsigned short P_lds[8][16][72];

    int srow = tid >> 3;
    int sc = (((tid & 7) ^ (srow & 7)) << 3);
    const unsigned short* kS = kbh + ((size_t)bh * SS + srow) * DD + sc;
    const unsigned short* vS = vt + ((size_t)bh * DD + srow) * SS + sc;

    int fidx[4];
    #pragma unroll
    for (int n = 0; n < 4; ++n) {
        int r = 16 * n + lq;
        fidx[n] = r * 64 + ((lg ^ (r & 7)) << 3);
    }

    // load Q fragments and apply RoPE in-register (pairs lane-local)
    const unsigned short* qrow = qbh + ((size_t)bh * SS + i) * DD + lg * 8;
    union { bf16x8 v; __bf16 e[8]; } uq0, uq1;
    uq0.v = *(const bf16x8*)qrow;          // d = lg*8 .. lg*8+7
    uq1.v = *(const bf16x8*)(qrow + 32);   // d = 32+lg*8 .. 32+lg*8+7
    {
        const float2* tbq = ropetab + (size_t)i * 32 + lg * 4;
        #pragma unroll
        for (int p = 0; p < 4; ++p) {
            float2 t0 = tbq[p];
            float x = (float)uq0.e[2 * p], y = (float)uq0.e[2 * p + 1];
            uq0.e[2 * p]     = (__bf16)((x * t0.x - y * t0.y) * 0.125f);
            uq0.e[2 * p + 1] = (__bf16)((y * t0.x + x * t0.y) * 0.125f);
            float2 t1 = tbq[16 + p];
            x = (float)uq1.e[2 * p]; y = (float)uq1.e[2 * p + 1];
            uq1.e[2 * p]     = (__bf16)((x * t1.x - y * t1.y) * 0.125f);
            uq1.e[2 * p + 1] = (__bf16)((y * t1.x + x * t1.y) * 0.125f);
        }
    }
    bf16x8 bq0 = uq0.v;
    bf16x8 bq1 = uq1.v;

    int jmin = i - WINDOW;
    int es = epstart[b * SS + i];
    if (es > jmin) jmin = es;
    float gi = gate[(size_t)bh * SS + i];

    float m = -1e30f, l = 0.f;
    f32x4 o[4];
    #pragma unroll
    for (int n = 0; n < 4; ++n) o[n] = (f32x4){0.f, 0.f, 0.f, 0.f};

    int jt0 = (q0 >= 512) ? ((q0 - 512) >> 6) : 0;
    int jt1 = (q0 + 127) >> 6;
    int nt = jt1 - jt0 + 1;
    int jb0 = jt0 * 64;

    for (int u = 0; u < nt; ++u) {
        int jbase = jb0 + 64 * u;

        __syncthreads();
        async_cp16(&Ks[tid * 8], kS + (size_t)jbase * DD);
        async_cp16(&Vs[tid * 8], vS + jbase);
        __syncthreads();

        f32x4 acc[4];
        #pragma unroll
        for (int n = 0; n < 4; ++n) acc[n] = (f32x4){0.f, 0.f, 0.f, 0.f};
        __builtin_amdgcn_s_setprio(1);
        #pragma unroll
        for (int n = 0; n < 4; ++n) {
            bf16x8 kf0 = *(const bf16x8*)&Ks[fidx[n]];
            bf16x8 kf1 = *(const bf16x8*)&Ks[fidx[n] ^ 32];
            acc[n] = __builtin_amdgcn_mfma_f32_16x16x32_bf16(kf0, bq0, acc[n], 0, 0, 0);
            acc[n] = __builtin_amdgcn_mfma_f32_16x16x32_bf16(kf1, bq1, acc[n], 0, 0, 0);
        }
        __builtin_amdgcn_s_setprio(0);

        int jb = jbase + lg * 4;
        #pragma unroll
        for (int n = 0; n < 4; ++n)
            #pragma unroll
            for (int r = 0; r < 4; ++r) {
                int j = jb + 16 * n + r;
                if (j < jmin || j > i) acc[n][r] = -3e38f;
            }

        float tm = -3e38f;
        #pragma unroll
        for (int n = 0; n < 4; ++n)
            tm = fmaxf(tm, fmaxf(fmaxf(acc[n][0], acc[n][1]), fmaxf(acc[n][2], acc[n][3])));
        tm = fmaxf(tm, __shfl_xor(tm, 16, 64));
        tm = fmaxf(tm, __shfl_xor(tm, 32, 64));
        float mnew = fmaxf(m, tm);
        float scale = __expf(m - mnew);
        float ts = 0.f;
        #pragma unroll
        for (int n = 0; n < 4; ++n)
            #pragma unroll
            for (int r = 0; r < 4; ++r) {
                float p = __expf(acc[n][r] - mnew);
                acc[n][r] = p;
                ts += p;
            }
        ts += __shfl_xor(ts, 16, 64);
        ts += __shfl_xor(ts, 32, 64);
        l = l * scale + ts;
        m = mnew;
        #pragma unroll
        for (int n = 0; n < 4; ++n) o[n] = o[n] * scale;

        #pragma unroll
        for (int n = 0; n < 4; ++n) {
            bf16x4 pv;
            pv[0] = (__bf16)acc[n][0]; pv[1] = (__bf16)acc[n][1];
            pv[2] = (__bf16)acc[n][2]; pv[3] = (__bf16)acc[n][3];
            *(bf16x4*)&P_lds[wave][lq][16 * n + lg * 4] = pv;
        }
        bf16x8 bp0 = *(const bf16x8*)&P_lds[wave][lq][lg * 8];
        bf16x8 bp1 = *(const bf16x8*)&P_lds[wave][lq][32 + lg * 8];

        __builtin_amdgcn_s_setprio(1);
        #pragma unroll
        for (int n = 0; n < 4; ++n) {
            bf16x8 vf0 = *(const bf16x8*)&Vs[fidx[n]];
            bf16x8 vf1 = *(const bf16x8*)&Vs[fidx[n] ^ 32];
            o[n] = __builtin_amdgcn_mfma_f32_16x16x32_bf16(vf0, bp0, o[n], 0, 0, 0);
            o[n] = __builtin_amdgcn_mfma_f32_16x16x32_bf16(vf1, bp1, o[n], 0, 0, 0);
        }
        __builtin_amdgcn_s_setprio(0);
    }

    float g = gi / l;
    #pragma unroll
    for (int n = 0; n < 4; ++n) {
        bf16x4 ov;
        ov[0] = (__bf16)(o[n][0] * g); ov[1] = (__bf16)(o[n][1] * g);
        ov[2] = (__bf16)(o[n][2] * g); ov[3] = (__bf16)(o[n][3] * g);
        *(bf16x4*)(ao + (((size_t)b * SS + i) * HH + h) * DD + 16 * n + lg * 4) = ov;
    }
}

// ------------------------------------------------------------------
extern "C" void kernel_launch(void* const* d_in, const int* in_sizes, int n_in,
                              void* d_out, int out_size, void* d_ws, size_t ws_size,
                              hipStream_t stream)
{
    const float* tokens = (const float*)d_in[0];
    const float* vres   = (const float*)d_in[1];
    const int*   ep     = (const int*)d_in[2];
    const float* Wq     = (const float*)d_in[3];
    const float* Wkv    = (const float*)d_in[4];
    const float* Wo     = (const float*)d_in[5];
    const float* Wg     = (const float*)d_in[6];
    const float* Wmix   = (const float*)d_in[7];
    float* out = (float*)d_out;

    char* wsb = (char*)d_ws;
    unsigned short* qbh  = (unsigned short*)(wsb + 0);         // 8 MB
    unsigned short* kbh  = (unsigned short*)(wsb + 8388608);   // 8 MB
    unsigned short* vb0  = (unsigned short*)(wsb + 16777216);  // 8 MB
    unsigned short* vtb  = (unsigned short*)(wsb + 25165824);  // 8 MB
    unsigned short* aob  = (unsigned short*)(wsb + 33554432);  // 8 MB
    unsigned short* tokA = (unsigned short*)(wsb + 41943040);  // 8 MB
    unsigned short* BtW  = (unsigned short*)(wsb + 50331648);  // 6 MB
    float* gatep = (float*)(wsb + 56623104);                   // 256 KB
    float* mixp  = (float*)(wsb + 56885248);                   // 256 KB
    int*   epst  = (int*)(wsb + 57147392);                     // 16 KB
    unsigned short* wgmt = (unsigned short*)(wsb + 57163776);  // 64 KB
    unsigned short* WotW = (unsigned short*)(wsb + 57229312);  // 2 MB
    float2* ropetab = (float2*)(wsb + 59326464);               // 512 KB

    prep_all_kernel<<<6544, 256, 0, stream>>>(tokens, tokA, Wq, Wkv, Wo, BtW, WotW,
                                              Wg, Wmix, wgmt, ep, epst, ropetab);
    projmix_kernel<<<1024, 256, 0, stream>>>(tokA, BtW, qbh, kbh, vb0,
                                             wgmt, gatep, mixp);
    rope_lerp_kernel<<<dim3(SS / 64, BB * HH), 256, 0, stream>>>(kbh, vb0, vres, mixp, vtb, ropetab);
    attn_mfma<<<512, 512, 0, stream>>>(qbh, kbh, vtb, epst, gatep, aob, ropetab);

    gemm_mfma<128, 64><<<dim3(16, 32), 256, 0, stream>>>(aob, WotW, out);
}